// Round 1
// baseline (390.379 us; speedup 1.0000x reference)
//
#include <hip/hip_runtime.h>
#include <math.h>

#define B_ 64
#define T_ 4096
#define D_ 256
#define U_ 64
#define RPB 32           // rows per block (2 strips of 16)
#define NPB (T_ / RPB)   // blocks per batch = 128
#define XPAD 264         // LDS x row stride (bf16 elems), 16B-odd (528B = 16*33)

typedef float f32x4 __attribute__((ext_vector_type(4)));
typedef short bf16x8 __attribute__((ext_vector_type(8)));

__device__ __forceinline__ unsigned short f2bf_rne(float f) {
    unsigned u = __float_as_uint(f);
    unsigned r = u + 0x7fffu + ((u >> 16) & 1u);
    return (unsigned short)(r >> 16);
}
__device__ __forceinline__ float bfbits2f(unsigned short s) {
    return __uint_as_float(((unsigned)s) << 16);
}

// Pack W [D,U] fp32 into MFMA B-fragment order, split hi/lo bf16.
// Fragment (ks,nt,lane,j): value = W[k = ks*32 + (lane>>4)*8 + j][n = nt*16 + (lane&15)]
__global__ __launch_bounds__(256) void wprep_kernel(
    const float* __restrict__ W, unsigned short* __restrict__ whi,
    unsigned short* __restrict__ wlo)
{
    int fi = blockIdx.x * 256 + threadIdx.x;   // 0..16383, grid=64
    int j    = fi & 7;
    int lane = (fi >> 3) & 63;
    int tile = fi >> 9;            // 0..31
    int nt = tile & 3, ks = tile >> 2;
    int k = ks * 32 + (lane >> 4) * 8 + j;
    int n = nt * 16 + (lane & 15);
    float w = W[k * U_ + n];
    unsigned short hi = f2bf_rne(w);
    unsigned short lo = f2bf_rne(w - bfbits2f(hi));
    whi[fi] = hi;
    wlo[fi] = lo;
}

// Fused main. Grid = 8192 blocks (32 rows each), 4 blocks/CU (16 waves/CU).
// R1 changes vs 370.9us baseline:
//  - B-frag loads sunk BELOW the staging barrier (stage-phase peak VGPR ~60
//    instead of ~120 at the 128-reg launch_bounds cliff -> no spill)
//  - esh broadcast + one barrier removed: every thread recomputes e for its
//    4 context rows from part[]; only wave0 writes wts/Zp (nobody waits on it)
//  - 3 barriers total (stage, part, red)
__global__ __launch_bounds__(256, 4) void fused_main(
    const float* __restrict__ x, const unsigned short* __restrict__ whi,
    const unsigned short* __restrict__ wlo, const float* __restrict__ bias,
    const float* __restrict__ uvec, float* __restrict__ wts,
    float* __restrict__ Zp, float* __restrict__ Pp)
{
    __shared__ unsigned short Ahi[RPB * XPAD];   // 16.9 KB
    __shared__ unsigned short Alo[RPB * XPAD];   // 16.9 KB
    __shared__ float part[RPB][4];               // 512 B

    int tid = threadIdx.x;
    int lane = tid & 63, wid = tid >> 6;
    int q = lane >> 4, r = lane & 15;

    int b = blockIdx.x / NPB;
    int pb = blockIdx.x % NPB;
    size_t row00 = (size_t)b * T_ + (size_t)pb * RPB;

    // tiny per-thread parameter loads: issue before staging, in flight under it
    int col = wid * 16 + r;
    float bv = bias[col], uv = uvec[col];

    // ---- cooperative stage: 2048 float4 = 32 rows x 256 cols, convert once ----
    {
        const float4* xs4 = (const float4*)(x + row00 * D_);
        float4 xs[8];
#pragma unroll
        for (int i = 0; i < 8; ++i) xs[i] = xs4[tid + i * 256];
#pragma unroll
        for (int i = 0; i < 8; ++i) {
            int f = tid + i * 256;
            int row = f >> 6, c4 = f & 63;
            float4 v = xs[i];
            unsigned short h0 = f2bf_rne(v.x), h1 = f2bf_rne(v.y),
                           h2 = f2bf_rne(v.z), h3 = f2bf_rne(v.w);
            unsigned short l0 = f2bf_rne(v.x - bfbits2f(h0)),
                           l1 = f2bf_rne(v.y - bfbits2f(h1)),
                           l2 = f2bf_rne(v.z - bfbits2f(h2)),
                           l3 = f2bf_rne(v.w - bfbits2f(h3));
            int base = row * XPAD + c4 * 4;
            uint2 hp = { (unsigned)h0 | ((unsigned)h1 << 16),
                         (unsigned)h2 | ((unsigned)h3 << 16) };
            uint2 lp = { (unsigned)l0 | ((unsigned)l1 << 16),
                         (unsigned)l2 | ((unsigned)l3 << 16) };
            *(uint2*)(&Ahi[base]) = hp;
            *(uint2*)(&Alo[base]) = lp;
        }
    }
    __syncthreads();

    // ---- B-fragments for this wave's column tile (nt = wid) ----
    // Loaded AFTER staging so 64 VGPRs are not live across the convert loop.
    // whi/wlo are 64 KB total and L2-resident after the first few blocks.
    bf16x8 Bh[8], Bl[8];
    {
        const bf16x8* whiV = (const bf16x8*)whi;
        const bf16x8* wloV = (const bf16x8*)wlo;
#pragma unroll
        for (int ks = 0; ks < 8; ++ks) {
            Bh[ks] = whiV[(ks * 4 + wid) * 64 + lane];
            Bl[ks] = wloV[(ks * 4 + wid) * 64 + lane];
        }
    }

    // ---- MFMA: 2 strips of 16 rows ----
#pragma unroll
    for (int s = 0; s < 2; ++s) {
        f32x4 acc = (f32x4){0.f, 0.f, 0.f, 0.f};
        int arow = (s * 16 + r) * XPAD + q * 8;
#pragma unroll
        for (int ks = 0; ks < 8; ++ks) {
            bf16x8 ahi = *(const bf16x8*)(&Ahi[arow + ks * 32]);
            bf16x8 alo = *(const bf16x8*)(&Alo[arow + ks * 32]);
            acc = __builtin_amdgcn_mfma_f32_16x16x32_bf16(ahi, Bh[ks], acc, 0, 0, 0);
            acc = __builtin_amdgcn_mfma_f32_16x16x32_bf16(ahi, Bl[ks], acc, 0, 0, 0);
            acc = __builtin_amdgcn_mfma_f32_16x16x32_bf16(alo, Bh[ks], acc, 0, 0, 0);
        }
        // score = tanh(acc+bias); p = score*u; reduce over this wave's 16 cols.
        float p0 = fmaf(1.f - 2.f / (__expf(2.f * (acc[0] + bv)) + 1.f), uv, 0.f);
        float p1 = fmaf(1.f - 2.f / (__expf(2.f * (acc[1] + bv)) + 1.f), uv, 0.f);
        float p2 = fmaf(1.f - 2.f / (__expf(2.f * (acc[2] + bv)) + 1.f), uv, 0.f);
        float p3 = fmaf(1.f - 2.f / (__expf(2.f * (acc[3] + bv)) + 1.f), uv, 0.f);
#pragma unroll
        for (int off = 1; off < 16; off <<= 1) {
            p0 += __shfl_xor(p0, off, 64);
            p1 += __shfl_xor(p1, off, 64);
            p2 += __shfl_xor(p2, off, 64);
            p3 += __shfl_xor(p3, off, 64);
        }
        if (r == 0) {
            int row = s * 16 + q * 4;
            part[row + 0][wid] = p0;
            part[row + 1][wid] = p1;
            part[row + 2][wid] = p2;
            part[row + 3][wid] = p3;
        }
    }
    __syncthreads();

    // ---- every thread: e for its 4 context rows (recomputed from part[]) ----
    int colg = tid & 31, ph = tid >> 5;     // 8 cols/thread, 8 row-phases
    float ew[4];
#pragma unroll
    for (int j = 0; j < 4; ++j) {
        int row = j * 8 + ph;
        float lg = (part[row][0] + part[row][1]) + (part[row][2] + part[row][3]);
        ew[j] = __expf(lg);
    }
    // wave0 alone: wts write + block Z partial (other waves proceed)
    if (wid == 0 && lane < RPB) {
        float lg = (part[lane][0] + part[lane][1]) + (part[lane][2] + part[lane][3]);
        float e = __expf(lg);
        wts[row00 + lane] = e;
        float z = e;
#pragma unroll
        for (int off = 1; off < 32; off <<= 1) z += __shfl_xor(z, off, 32);
        if (lane == 0) Zp[blockIdx.x] = z;
    }

    // ---- context: P[col] = sum_rows e[row]*xhi[row][col] from LDS ----
    float pacc[8];
#pragma unroll
    for (int j = 0; j < 8; ++j) pacc[j] = 0.f;
#pragma unroll
    for (int i = 0; i < 4; ++i) {
        int row = i * 8 + ph;
        float w = ew[i];
        union { uint4 u; unsigned short sh[8]; } v;
        v.u = *(const uint4*)(&Ahi[row * XPAD + colg * 8]);
#pragma unroll
        for (int j = 0; j < 8; ++j)
            pacc[j] = fmaf(w, bfbits2f(v.sh[j]), pacc[j]);
    }
    // Alo reads all finished before the part-barrier -> safe to reuse as reduce buf
    float* red = (float*)Alo;        // 8 KB
#pragma unroll
    for (int j = 0; j < 8; ++j) red[ph * 256 + colg * 8 + j] = pacc[j];
    __syncthreads();
    float ssum = 0.f;
#pragma unroll
    for (int p = 0; p < 8; ++p) ssum += red[p * 256 + tid];
    Pp[(size_t)blockIdx.x * D_ + tid] = ssum;
}

// Finalize: Z_b = sum of NPB partials; ctx = sum(Pp)/Z; wts *= 1/Z.
__global__ __launch_bounds__(256) void finalize_kernel(
    float* __restrict__ wts, const float* __restrict__ Zp,
    const float* __restrict__ Pp, float* __restrict__ ctx)
{
    int b = blockIdx.x;
    int tid = threadIdx.x;
    float Z = 0.f;
#pragma unroll 8
    for (int i = 0; i < NPB; ++i) Z += Zp[b * NPB + i];   // uniform s_loads
    float invZ = 1.f / Z;

    float s = 0.f;
#pragma unroll 4
    for (int i = 0; i < NPB; ++i) s += Pp[(size_t)(b * NPB + i) * D_ + tid];
    ctx[b * D_ + tid] = s * invZ;

    float4* wp = (float4*)(wts + (size_t)b * T_);
#pragma unroll
    for (int i = 0; i < T_ / 4 / 256; ++i) {
        float4 v = wp[tid + i * 256];
        v.x *= invZ; v.y *= invZ; v.z *= invZ; v.w *= invZ;
        wp[tid + i * 256] = v;
    }
}

extern "C" void kernel_launch(void* const* d_in, const int* in_sizes, int n_in,
                              void* d_out, int out_size, void* d_ws, size_t ws_size,
                              hipStream_t stream) {
    const float* x    = (const float*)d_in[0];   // [B,T,D]
    const float* W    = (const float*)d_in[1];   // [D,U]
    const float* bias = (const float*)d_in[2];   // [U]
    const float* uvec = (const float*)d_in[3];   // [U,1]

    float* out = (float*)d_out;
    float* ctx = out;            // context: B*D floats
    float* wts = out + B_ * D_;  // attention weights: B*T floats (e between kernels)

    unsigned short* whi = (unsigned short*)d_ws;     // 32 KB
    unsigned short* wlo = whi + D_ * U_;             // 32 KB
    float* Zp = (float*)(wlo + D_ * U_);             // 8192 partial Z
    float* Pp = Zp + B_ * NPB;                       // 8192 x 256 partial context

    wprep_kernel<<<D_ * U_ / 256, 256, 0, stream>>>(W, whi, wlo);
    fused_main<<<(B_ * T_) / RPB, 256, 0, stream>>>(x, whi, wlo, bias, uvec, wts, Zp, Pp);
    finalize_kernel<<<B_, 256, 0, stream>>>(wts, Zp, Pp, ctx);
}

// Round 2
// 369.705 us; speedup vs baseline: 1.0559x; 1.0559x over previous
//
#include <hip/hip_runtime.h>
#include <math.h>

#define B_ 64
#define T_ 4096
#define D_ 256
#define U_ 64
#define RPB 32           // rows per block (2 strips of 16)
#define NPB (T_ / RPB)   // blocks per batch = 128
#define XPAD 264         // LDS x row stride (bf16 elems), 16B-odd (528B = 16*33)

typedef float f32x4 __attribute__((ext_vector_type(4)));
typedef short bf16x8 __attribute__((ext_vector_type(8)));

__device__ __forceinline__ unsigned short f2bf_rne(float f) {
    unsigned u = __float_as_uint(f);
    unsigned r = u + 0x7fffu + ((u >> 16) & 1u);
    return (unsigned short)(r >> 16);
}
__device__ __forceinline__ float bfbits2f(unsigned short s) {
    return __uint_as_float(((unsigned)s) << 16);
}

// Pack W [D,U] fp32 into MFMA B-fragment order, split hi/lo bf16.
// Fragment (ks,nt,lane,j): value = W[k = ks*32 + (lane>>4)*8 + j][n = nt*16 + (lane&15)]
__global__ __launch_bounds__(256) void wprep_kernel(
    const float* __restrict__ W, unsigned short* __restrict__ whi,
    unsigned short* __restrict__ wlo)
{
    int fi = blockIdx.x * 256 + threadIdx.x;   // 0..16383, grid=64
    int j    = fi & 7;
    int lane = (fi >> 3) & 63;
    int tile = fi >> 9;            // 0..31
    int nt = tile & 3, ks = tile >> 2;
    int k = ks * 32 + (lane >> 4) * 8 + j;
    int n = nt * 16 + (lane & 15);
    float w = W[k * U_ + n];
    unsigned short hi = f2bf_rne(w);
    unsigned short lo = f2bf_rne(w - bfbits2f(hi));
    whi[fi] = hi;
    wlo[fi] = lo;
}

// Fused main. Grid = 8192 blocks (32 rows each), 4 blocks/CU (16 waves/CU).
// R2 vs R1 (390.4us) / R0 (370.9us):
//  - B-frag loads restored to BEFORE staging (R1's sink serialized ~64KB of L2
//    reads per block behind the barrier: predicted +15us, measured +19.5us)
//  - staging split into 2 batches of 4 float4: peak live VGPR ~106 (<128 cap)
//    while keeping 64KB/CU of loads in flight (BW saturation needs ~9KB)
//  - keeps R1's barrier removal (e recomputed from part[], wave0-only wts/Zp)
__global__ __launch_bounds__(256, 4) void fused_main(
    const float* __restrict__ x, const unsigned short* __restrict__ whi,
    const unsigned short* __restrict__ wlo, const float* __restrict__ bias,
    const float* __restrict__ uvec, float* __restrict__ wts,
    float* __restrict__ Zp, float* __restrict__ Pp)
{
    __shared__ unsigned short Ahi[RPB * XPAD];   // 16.9 KB
    __shared__ unsigned short Alo[RPB * XPAD];   // 16.9 KB
    __shared__ float part[RPB][4];               // 512 B

    int tid = threadIdx.x;
    int lane = tid & 63, wid = tid >> 6;
    int q = lane >> 4, r = lane & 15;

    int b = blockIdx.x / NPB;
    int pb = blockIdx.x % NPB;
    size_t row00 = (size_t)b * T_ + (size_t)pb * RPB;

    // tiny per-thread parameter loads: in flight under everything below
    int col = wid * 16 + r;
    float bv = bias[col], uv = uvec[col];

    // ---- B-fragments for this wave's column tile (nt = wid) ----
    // Issued BEFORE staging: the ~64KB/block of L2 reads hide under the x HBM
    // loads instead of serializing after the barrier (R1 regression).
    bf16x8 Bh[8], Bl[8];
    {
        const bf16x8* whiV = (const bf16x8*)whi;
        const bf16x8* wloV = (const bf16x8*)wlo;
#pragma unroll
        for (int ks = 0; ks < 8; ++ks) {
            Bh[ks] = whiV[(ks * 4 + wid) * 64 + lane];
            Bl[ks] = wloV[(ks * 4 + wid) * 64 + lane];
        }
    }

    // ---- cooperative stage: 32 rows x 256 cols, convert once, 2 batches ----
    {
        const float4* xs4 = (const float4*)(x + row00 * D_);
#pragma unroll
        for (int h = 0; h < 2; ++h) {
            float4 xs[4];
#pragma unroll
            for (int i = 0; i < 4; ++i) xs[i] = xs4[tid + (h * 4 + i) * 256];
#pragma unroll
            for (int i = 0; i < 4; ++i) {
                int f = tid + (h * 4 + i) * 256;
                int row = f >> 6, c4 = f & 63;
                float4 v = xs[i];
                unsigned short h0 = f2bf_rne(v.x), h1 = f2bf_rne(v.y),
                               h2 = f2bf_rne(v.z), h3 = f2bf_rne(v.w);
                unsigned short l0 = f2bf_rne(v.x - bfbits2f(h0)),
                               l1 = f2bf_rne(v.y - bfbits2f(h1)),
                               l2 = f2bf_rne(v.z - bfbits2f(h2)),
                               l3 = f2bf_rne(v.w - bfbits2f(h3));
                int base = row * XPAD + c4 * 4;
                uint2 hp = { (unsigned)h0 | ((unsigned)h1 << 16),
                             (unsigned)h2 | ((unsigned)h3 << 16) };
                uint2 lp = { (unsigned)l0 | ((unsigned)l1 << 16),
                             (unsigned)l2 | ((unsigned)l3 << 16) };
                *(uint2*)(&Ahi[base]) = hp;
                *(uint2*)(&Alo[base]) = lp;
            }
        }
    }
    __syncthreads();

    // ---- MFMA: 2 strips of 16 rows ----
#pragma unroll
    for (int s = 0; s < 2; ++s) {
        f32x4 acc = (f32x4){0.f, 0.f, 0.f, 0.f};
        int arow = (s * 16 + r) * XPAD + q * 8;
#pragma unroll
        for (int ks = 0; ks < 8; ++ks) {
            bf16x8 ahi = *(const bf16x8*)(&Ahi[arow + ks * 32]);
            bf16x8 alo = *(const bf16x8*)(&Alo[arow + ks * 32]);
            acc = __builtin_amdgcn_mfma_f32_16x16x32_bf16(ahi, Bh[ks], acc, 0, 0, 0);
            acc = __builtin_amdgcn_mfma_f32_16x16x32_bf16(ahi, Bl[ks], acc, 0, 0, 0);
            acc = __builtin_amdgcn_mfma_f32_16x16x32_bf16(alo, Bh[ks], acc, 0, 0, 0);
        }
        // score = tanh(acc+bias); p = score*u; reduce over this wave's 16 cols.
        float p0 = fmaf(1.f - 2.f / (__expf(2.f * (acc[0] + bv)) + 1.f), uv, 0.f);
        float p1 = fmaf(1.f - 2.f / (__expf(2.f * (acc[1] + bv)) + 1.f), uv, 0.f);
        float p2 = fmaf(1.f - 2.f / (__expf(2.f * (acc[2] + bv)) + 1.f), uv, 0.f);
        float p3 = fmaf(1.f - 2.f / (__expf(2.f * (acc[3] + bv)) + 1.f), uv, 0.f);
#pragma unroll
        for (int off = 1; off < 16; off <<= 1) {
            p0 += __shfl_xor(p0, off, 64);
            p1 += __shfl_xor(p1, off, 64);
            p2 += __shfl_xor(p2, off, 64);
            p3 += __shfl_xor(p3, off, 64);
        }
        if (r == 0) {
            int row = s * 16 + q * 4;
            part[row + 0][wid] = p0;
            part[row + 1][wid] = p1;
            part[row + 2][wid] = p2;
            part[row + 3][wid] = p3;
        }
    }
    __syncthreads();

    // ---- every thread: e for its 4 context rows (recomputed from part[]) ----
    int colg = tid & 31, ph = tid >> 5;     // 8 cols/thread, 8 row-phases
    float ew[4];
#pragma unroll
    for (int j = 0; j < 4; ++j) {
        int row = j * 8 + ph;
        float lg = (part[row][0] + part[row][1]) + (part[row][2] + part[row][3]);
        ew[j] = __expf(lg);
    }
    // wave0 alone: wts write + block Z partial (other waves proceed)
    if (wid == 0 && lane < RPB) {
        float lg = (part[lane][0] + part[lane][1]) + (part[lane][2] + part[lane][3]);
        float e = __expf(lg);
        wts[row00 + lane] = e;
        float z = e;
#pragma unroll
        for (int off = 1; off < 32; off <<= 1) z += __shfl_xor(z, off, 32);
        if (lane == 0) Zp[blockIdx.x] = z;
    }

    // ---- context: P[col] = sum_rows e[row]*xhi[row][col] from LDS ----
    float pacc[8];
#pragma unroll
    for (int j = 0; j < 8; ++j) pacc[j] = 0.f;
#pragma unroll
    for (int i = 0; i < 4; ++i) {
        int row = i * 8 + ph;
        float w = ew[i];
        union { uint4 u; unsigned short sh[8]; } v;
        v.u = *(const uint4*)(&Ahi[row * XPAD + colg * 8]);
#pragma unroll
        for (int j = 0; j < 8; ++j)
            pacc[j] = fmaf(w, bfbits2f(v.sh[j]), pacc[j]);
    }
    // Alo reads all finished before the part-barrier -> safe to reuse as reduce buf
    float* red = (float*)Alo;        // 8 KB
#pragma unroll
    for (int j = 0; j < 8; ++j) red[ph * 256 + colg * 8 + j] = pacc[j];
    __syncthreads();
    float ssum = 0.f;
#pragma unroll
    for (int p = 0; p < 8; ++p) ssum += red[p * 256 + tid];
    Pp[(size_t)blockIdx.x * D_ + tid] = ssum;
}

// Finalize: Z_b = sum of NPB partials; ctx = sum(Pp)/Z; wts *= 1/Z.
__global__ __launch_bounds__(256) void finalize_kernel(
    float* __restrict__ wts, const float* __restrict__ Zp,
    const float* __restrict__ Pp, float* __restrict__ ctx)
{
    int b = blockIdx.x;
    int tid = threadIdx.x;
    float Z = 0.f;
#pragma unroll 8
    for (int i = 0; i < NPB; ++i) Z += Zp[b * NPB + i];   // uniform s_loads
    float invZ = 1.f / Z;

    float s = 0.f;
#pragma unroll 4
    for (int i = 0; i < NPB; ++i) s += Pp[(size_t)(b * NPB + i) * D_ + tid];
    ctx[b * D_ + tid] = s * invZ;

    float4* wp = (float4*)(wts + (size_t)b * T_);
#pragma unroll
    for (int i = 0; i < T_ / 4 / 256; ++i) {
        float4 v = wp[tid + i * 256];
        v.x *= invZ; v.y *= invZ; v.z *= invZ; v.w *= invZ;
        wp[tid + i * 256] = v;
    }
}

extern "C" void kernel_launch(void* const* d_in, const int* in_sizes, int n_in,
                              void* d_out, int out_size, void* d_ws, size_t ws_size,
                              hipStream_t stream) {
    const float* x    = (const float*)d_in[0];   // [B,T,D]
    const float* W    = (const float*)d_in[1];   // [D,U]
    const float* bias = (const float*)d_in[2];   // [U]
    const float* uvec = (const float*)d_in[3];   // [U,1]

    float* out = (float*)d_out;
    float* ctx = out;            // context: B*D floats
    float* wts = out + B_ * D_;  // attention weights: B*T floats (e between kernels)

    unsigned short* whi = (unsigned short*)d_ws;     // 32 KB
    unsigned short* wlo = whi + D_ * U_;             // 32 KB
    float* Zp = (float*)(wlo + D_ * U_);             // 8192 partial Z
    float* Pp = Zp + B_ * NPB;                       // 8192 x 256 partial context

    wprep_kernel<<<D_ * U_ / 256, 256, 0, stream>>>(W, whi, wlo);
    fused_main<<<(B_ * T_) / RPB, 256, 0, stream>>>(x, whi, wlo, bias, uvec, wts, Zp, Pp);
    finalize_kernel<<<B_, 256, 0, stream>>>(wts, Zp, Pp, ctx);
}

// Round 3
// 368.251 us; speedup vs baseline: 1.0601x; 1.0039x over previous
//
#include <hip/hip_runtime.h>
#include <math.h>

#define B_ 64
#define T_ 4096
#define D_ 256
#define U_ 64
#define RPB 32           // rows per block (2 strips of 16)
#define NPB (T_ / RPB)   // blocks per batch = 128
#define XPAD 264         // LDS x row stride (bf16 elems), 16B-odd (528B = 16*33)

typedef float f32x4 __attribute__((ext_vector_type(4)));
typedef short bf16x8 __attribute__((ext_vector_type(8)));

__device__ __forceinline__ unsigned short f2bf_rne(float f) {
    unsigned u = __float_as_uint(f);
    unsigned r = u + 0x7fffu + ((u >> 16) & 1u);
    return (unsigned short)(r >> 16);
}
__device__ __forceinline__ float bfbits2f(unsigned short s) {
    return __uint_as_float(((unsigned)s) << 16);
}

// Pack W [D,U] fp32 into MFMA B-fragment order, split hi/lo bf16.
// Fragment (ks,nt,lane,j): value = W[k = ks*32 + (lane>>4)*8 + j][n = nt*16 + (lane&15)]
__global__ __launch_bounds__(256) void wprep_kernel(
    const float* __restrict__ W, unsigned short* __restrict__ whi,
    unsigned short* __restrict__ wlo)
{
    int fi = blockIdx.x * 256 + threadIdx.x;   // 0..16383, grid=64
    int j    = fi & 7;
    int lane = (fi >> 3) & 63;
    int tile = fi >> 9;            // 0..31
    int nt = tile & 3, ks = tile >> 2;
    int k = ks * 32 + (lane >> 4) * 8 + j;
    int n = nt * 16 + (lane & 15);
    float w = W[k * U_ + n];
    unsigned short hi = f2bf_rne(w);
    unsigned short lo = f2bf_rne(w - bfbits2f(hi));
    whi[fi] = hi;
    wlo[fi] = lo;
}

// Fused main. Grid = 8192 blocks (32 rows each), 4 blocks/CU (16 waves/CU).
// R3 vs R2 (369.7us):
//  - stage via __builtin_amdgcn_global_load_lds width=16: x tile lands in LDS
//    as fp32 with NO VGPR round-trip (linear dest == global order). Then one
//    LDS->reg->convert->LDS pass (overlaid: fp32 region is reused for the
//    bf16 hi/lo buffers after a read barrier). Removes the 32-VGPR xs[] live
//    range at the 128-reg cap and makes HBM issue maximally dense.
//  - LDS: 33.8KB union + part = same 4 blocks/CU as before.
__global__ __launch_bounds__(256, 4) void fused_main(
    const float* __restrict__ x, const unsigned short* __restrict__ whi,
    const unsigned short* __restrict__ wlo, const float* __restrict__ bias,
    const float* __restrict__ uvec, float* __restrict__ wts,
    float* __restrict__ Zp, float* __restrict__ Pp)
{
    // union region: [0, 32768) = fp32 x tile during glds stage;
    // after convert: [0, 16896) = Ahi, [16896, 33792) = Alo (bf16, XPAD layout)
    __shared__ __align__(16) unsigned char smem[RPB * XPAD * 4];  // 33,792 B
    __shared__ float part[RPB][4];               // 512 B

    unsigned short* Ahi = (unsigned short*)smem;
    unsigned short* Alo = (unsigned short*)(smem + RPB * XPAD * 2);
    float* xf = (float*)smem;

    int tid = threadIdx.x;
    int lane = tid & 63, wid = tid >> 6;
    int q = lane >> 4, r = lane & 15;

    int b = blockIdx.x / NPB;
    int pb = blockIdx.x % NPB;
    size_t row00 = (size_t)b * T_ + (size_t)pb * RPB;

    // tiny per-thread parameter loads: in flight under everything below
    int col = wid * 16 + r;
    float bv = bias[col], uv = uvec[col];

    // ---- B-fragments for this wave's column tile (nt = wid) ----
    // Issued BEFORE staging: ~64KB/block of L2 reads hide under the x HBM
    // stream (R1 showed sinking them costs +19.5us).
    bf16x8 Bh[8], Bl[8];
    {
        const bf16x8* whiV = (const bf16x8*)whi;
        const bf16x8* wloV = (const bf16x8*)wlo;
#pragma unroll
        for (int ks = 0; ks < 8; ++ks) {
            Bh[ks] = whiV[(ks * 4 + wid) * 64 + lane];
            Bl[ks] = wloV[(ks * 4 + wid) * 64 + lane];
        }
    }

    // ---- stage 1: glds 32 KB fp32 tile, linear, no VGPR round-trip ----
    // chunk = 1KB = 256 floats; wave wid handles chunks wid*8 .. wid*8+7.
    // Per call: per-lane global addr = base + chunk*1KB + lane*16B;
    // LDS dest = wave-uniform (xf + chunk*256), HW scatters lane*16B.
    {
        const float* gbase = x + row00 * D_;
#pragma unroll
        for (int i = 0; i < 8; ++i) {
            int chunk = wid * 8 + i;
            const void* gp = (const void*)(gbase + chunk * 256 + lane * 4);
            void* lp = (void*)(xf + chunk * 256);
            __builtin_amdgcn_global_load_lds(
                (const __attribute__((address_space(1))) void*)gp,
                (__attribute__((address_space(3))) void*)lp, 16, 0, 0);
        }
    }
    __syncthreads();   // drains vmcnt: fp32 tile complete in LDS

    // ---- stage 2: read own floats to regs (before overlay overwrite) ----
    f32x4 xs[8];
#pragma unroll
    for (int i = 0; i < 8; ++i)
        xs[i] = *(const f32x4*)(xf + (size_t)(tid + i * 256) * 4);
    __syncthreads();   // ALL fp32 reads done before ANY bf16 writes

    // ---- stage 3: convert once, write hi/lo (identical layout to R2) ----
#pragma unroll
    for (int i = 0; i < 8; ++i) {
        int f = tid + i * 256;
        int row = f >> 6, c4 = f & 63;
        f32x4 v = xs[i];
        unsigned short h0 = f2bf_rne(v[0]), h1 = f2bf_rne(v[1]),
                       h2 = f2bf_rne(v[2]), h3 = f2bf_rne(v[3]);
        unsigned short l0 = f2bf_rne(v[0] - bfbits2f(h0)),
                       l1 = f2bf_rne(v[1] - bfbits2f(h1)),
                       l2 = f2bf_rne(v[2] - bfbits2f(h2)),
                       l3 = f2bf_rne(v[3] - bfbits2f(h3));
        int base = row * XPAD + c4 * 4;
        uint2 hp = { (unsigned)h0 | ((unsigned)h1 << 16),
                     (unsigned)h2 | ((unsigned)h3 << 16) };
        uint2 lp = { (unsigned)l0 | ((unsigned)l1 << 16),
                     (unsigned)l2 | ((unsigned)l3 << 16) };
        *(uint2*)(&Ahi[base]) = hp;
        *(uint2*)(&Alo[base]) = lp;
    }
    __syncthreads();

    // ---- MFMA: 2 strips of 16 rows ----
#pragma unroll
    for (int s = 0; s < 2; ++s) {
        f32x4 acc = (f32x4){0.f, 0.f, 0.f, 0.f};
        int arow = (s * 16 + r) * XPAD + q * 8;
#pragma unroll
        for (int ks = 0; ks < 8; ++ks) {
            bf16x8 ahi = *(const bf16x8*)(&Ahi[arow + ks * 32]);
            bf16x8 alo = *(const bf16x8*)(&Alo[arow + ks * 32]);
            acc = __builtin_amdgcn_mfma_f32_16x16x32_bf16(ahi, Bh[ks], acc, 0, 0, 0);
            acc = __builtin_amdgcn_mfma_f32_16x16x32_bf16(ahi, Bl[ks], acc, 0, 0, 0);
            acc = __builtin_amdgcn_mfma_f32_16x16x32_bf16(alo, Bh[ks], acc, 0, 0, 0);
        }
        // score = tanh(acc+bias); p = score*u; reduce over this wave's 16 cols.
        float p0 = fmaf(1.f - 2.f / (__expf(2.f * (acc[0] + bv)) + 1.f), uv, 0.f);
        float p1 = fmaf(1.f - 2.f / (__expf(2.f * (acc[1] + bv)) + 1.f), uv, 0.f);
        float p2 = fmaf(1.f - 2.f / (__expf(2.f * (acc[2] + bv)) + 1.f), uv, 0.f);
        float p3 = fmaf(1.f - 2.f / (__expf(2.f * (acc[3] + bv)) + 1.f), uv, 0.f);
#pragma unroll
        for (int off = 1; off < 16; off <<= 1) {
            p0 += __shfl_xor(p0, off, 64);
            p1 += __shfl_xor(p1, off, 64);
            p2 += __shfl_xor(p2, off, 64);
            p3 += __shfl_xor(p3, off, 64);
        }
        if (r == 0) {
            int row = s * 16 + q * 4;
            part[row + 0][wid] = p0;
            part[row + 1][wid] = p1;
            part[row + 2][wid] = p2;
            part[row + 3][wid] = p3;
        }
    }
    __syncthreads();

    // ---- every thread: e for its 4 context rows (recomputed from part[]) ----
    int colg = tid & 31, ph = tid >> 5;     // 8 cols/thread, 8 row-phases
    float ew[4];
#pragma unroll
    for (int j = 0; j < 4; ++j) {
        int row = j * 8 + ph;
        float lg = (part[row][0] + part[row][1]) + (part[row][2] + part[row][3]);
        ew[j] = __expf(lg);
    }
    // wave0 alone: wts write + block Z partial (other waves proceed)
    if (wid == 0 && lane < RPB) {
        float lg = (part[lane][0] + part[lane][1]) + (part[lane][2] + part[lane][3]);
        float e = __expf(lg);
        wts[row00 + lane] = e;
        float z = e;
#pragma unroll
        for (int off = 1; off < 32; off <<= 1) z += __shfl_xor(z, off, 32);
        if (lane == 0) Zp[blockIdx.x] = z;
    }

    // ---- context: P[col] = sum_rows e[row]*xhi[row][col] from LDS ----
    float pacc[8];
#pragma unroll
    for (int j = 0; j < 8; ++j) pacc[j] = 0.f;
#pragma unroll
    for (int i = 0; i < 4; ++i) {
        int row = i * 8 + ph;
        float w = ew[i];
        union { uint4 u; unsigned short sh[8]; } v;
        v.u = *(const uint4*)(&Ahi[row * XPAD + colg * 8]);
#pragma unroll
        for (int j = 0; j < 8; ++j)
            pacc[j] = fmaf(w, bfbits2f(v.sh[j]), pacc[j]);
    }
    // Alo reads all finished before the part-barrier -> safe to reuse as reduce buf
    float* red = (float*)Alo;        // 8 KB
#pragma unroll
    for (int j = 0; j < 8; ++j) red[ph * 256 + colg * 8 + j] = pacc[j];
    __syncthreads();
    float ssum = 0.f;
#pragma unroll
    for (int p = 0; p < 8; ++p) ssum += red[p * 256 + tid];
    Pp[(size_t)blockIdx.x * D_ + tid] = ssum;
}

// Finalize, 4x parallel: grid = B*4 blocks. Block (b,p) handles a 64-col
// quarter of ctx and a 1024-row quarter of wts. Z computed redundantly
// (128 L2-hot scalar loads). Was 64 blocks = 1 wave/CU latency-bound tail.
__global__ __launch_bounds__(256) void finalize_kernel(
    float* __restrict__ wts, const float* __restrict__ Zp,
    const float* __restrict__ Pp, float* __restrict__ ctx)
{
    __shared__ float red2[4][64];
    int bp = blockIdx.x;          // 0..255
    int b = bp >> 2, p = bp & 3;
    int tid = threadIdx.x;

    float Z = 0.f;
#pragma unroll 8
    for (int i = 0; i < NPB; ++i) Z += Zp[b * NPB + i];   // uniform s_loads
    float invZ = 1.f / Z;

    // ctx quarter: col = p*64 + (tid&63); row-quarter g = tid>>6 sums 32 rows
    int c = tid & 63, g = tid >> 6;
    float s = 0.f;
#pragma unroll 4
    for (int i = 0; i < 32; ++i)
        s += Pp[(size_t)(b * NPB + g * 32 + i) * D_ + p * 64 + c];
    red2[g][c] = s;
    __syncthreads();
    if (tid < 64) {
        float t = (red2[0][tid] + red2[1][tid]) + (red2[2][tid] + red2[3][tid]);
        ctx[b * D_ + p * 64 + tid] = t * invZ;
    }

    // wts quarter: 1024 rows, 256 threads x 1 float4
    float4* wp = (float4*)(wts + (size_t)b * T_ + (size_t)p * 1024);
    float4 v = wp[tid];
    v.x *= invZ; v.y *= invZ; v.z *= invZ; v.w *= invZ;
    wp[tid] = v;
}

extern "C" void kernel_launch(void* const* d_in, const int* in_sizes, int n_in,
                              void* d_out, int out_size, void* d_ws, size_t ws_size,
                              hipStream_t stream) {
    const float* x    = (const float*)d_in[0];   // [B,T,D]
    const float* W    = (const float*)d_in[1];   // [D,U]
    const float* bias = (const float*)d_in[2];   // [U]
    const float* uvec = (const float*)d_in[3];   // [U,1]

    float* out = (float*)d_out;
    float* ctx = out;            // context: B*D floats
    float* wts = out + B_ * D_;  // attention weights: B*T floats (e between kernels)

    unsigned short* whi = (unsigned short*)d_ws;     // 32 KB
    unsigned short* wlo = whi + D_ * U_;             // 32 KB
    float* Zp = (float*)(wlo + D_ * U_);             // 8192 partial Z
    float* Pp = Zp + B_ * NPB;                       // 8192 x 256 partial context

    wprep_kernel<<<D_ * U_ / 256, 256, 0, stream>>>(W, whi, wlo);
    fused_main<<<(B_ * T_) / RPB, 256, 0, stream>>>(x, whi, wlo, bias, uvec, wts, Zp, Pp);
    finalize_kernel<<<B_ * 4, 256, 0, stream>>>(wts, Zp, Pp, ctx);
}